// Round 10
// baseline (358.683 us; speedup 1.0000x reference)
//
#include <hip/hip_runtime.h>
#include <hip/hip_bf16.h>

#define MINN 1e-15f
#define MAXN (1.0f - 4e-3f)
#define ATMAX 3.1063031f   // atanhf(1 - 4e-3)

#define NBH 9              // log2(nodes per bucket)
#define BNODES 512
#define BCAP 10240         // staging capacity per bucket
#define BWIN (BCAP + 4 * BNODES)
#define PBE 8192           // edges per pass-B block

typedef short short8 __attribute__((ext_vector_type(8)));
typedef float f32x4 __attribute__((ext_vector_type(4)));

__device__ __forceinline__ float wsum(float v) {
    v += __shfl_xor(v, 32, 64);
    v += __shfl_xor(v, 16, 64);
    v += __shfl_xor(v, 8, 64);
    v += __shfl_xor(v, 4, 64);
    v += __shfl_xor(v, 2, 64);
    v += __shfl_xor(v, 1, 64);
    return v;
}

// truncation split: f ~= bf16(hi) + bf16(lo), combined rel err ~2^-18
__device__ __forceinline__ void splitf(float f, short& hi, short& lo) {
    unsigned u = __float_as_uint(f);
    hi = (short)(u >> 16);
    float r = f - __uint_as_float(u & 0xffff0000u);
    lo = (short)(__float_as_uint(r) >> 16);
}

__device__ __forceinline__ unsigned packsplit_hi(short ha, short hb) {
    return (unsigned)(unsigned short)ha | ((unsigned)(unsigned short)hb << 16);
}

// RNE bf16 pack of two floats
__device__ __forceinline__ unsigned pack_bf16(float a, float b) {
    unsigned ua = __float_as_uint(a);
    unsigned ub = __float_as_uint(b);
    ua = (ua + 0x7fffu + ((ua >> 16) & 1u)) >> 16;
    ub = (ub + 0x7fffu + ((ub >> 16) & 1u)) & 0xffff0000u;
    return ua | ub;
}

// fast transcendentals (args >= 0 in all uses; err ~2e-7)
__device__ __forceinline__ float tanh_fast(float x) {
    float e = __expf(2.f * x);
    return (e - 1.f) * __builtin_amdgcn_rcpf(e + 1.f);
}
__device__ __forceinline__ float atanh_fast(float x) {
    return 0.5f * __logf((1.f + x) * __builtin_amdgcn_rcpf(1.f - x));
}

// ---------------- pass B: bin edges into 512-node buckets ----------------
__global__ __launch_bounds__(256) void k_bucket(const int* __restrict__ src, const int* __restrict__ dst,
                                                const float* __restrict__ ew, int* __restrict__ gcur,
                                                int2* __restrict__ staging, int E, int NBUCK) {
    __shared__ int hist[512];
    const int tid = threadIdx.x;
    const int e0 = blockIdx.x * PBE;
    for (int i = tid; i < 512; i += 256) hist[i] = 0;
    __syncthreads();
    #pragma unroll 4
    for (int j = 0; j < PBE / 256; j++) {
        int e = e0 + j * 256 + tid;
        if (e < E) atomicAdd(&hist[dst[e] >> NBH], 1);
    }
    __syncthreads();
    for (int b = tid; b < NBUCK; b += 256) {
        int c = hist[b];
        hist[b] = c ? atomicAdd(&gcur[b], c) : 0;
    }
    __syncthreads();
    #pragma unroll 4
    for (int j = 0; j < PBE / 256; j++) {
        int e = e0 + j * 256 + tid;
        if (e < E) {
            int d = dst[e];
            int bkt = d >> NBH;
            int pos = atomicAdd(&hist[bkt], 1);
            if (pos < BCAP)
                staging[(size_t)bkt * BCAP + pos] =
                    make_int2((src[e] & 0x1FFFF) | ((d & (BNODES - 1)) << 17), __float_as_int(ew[e]));
        }
    }
}

// ---------------- pass C: per-bucket CSR build ----------------
__global__ __launch_bounds__(256) void k_cbuild(const int* __restrict__ gcur, const int2* __restrict__ staging,
                                                int2* __restrict__ csr, int2* __restrict__ rp2, int N) {
    __shared__ int cnt[BNODES];
    __shared__ int base[BNODES];
    __shared__ int sbuf[256];
    const int tid = threadIdx.x;
    const int b = blockIdx.x;
    const int bcnt = min(gcur[b], BCAP);
    const int wbase = b * BWIN;
    const int2* st = staging + (size_t)b * BCAP;

    for (int i = tid; i < BNODES; i += 256) cnt[i] = 0;
    __syncthreads();
    for (int i = tid; i < bcnt; i += 256) {
        int nl = (st[i].x >> 17) & (BNODES - 1);
        atomicAdd(&cnt[nl], 1);
    }
    __syncthreads();
    int p0 = (cnt[2 * tid] + 3) & ~3;
    int p1 = (cnt[2 * tid + 1] + 3) & ~3;
    int s = p0 + p1;
    sbuf[tid] = s;
    __syncthreads();
    for (int off = 1; off < 256; off <<= 1) {
        int add = (tid >= off) ? sbuf[tid - off] : 0;
        __syncthreads();
        sbuf[tid] += add;
        __syncthreads();
    }
    int excl = sbuf[tid] - s;
    base[2 * tid] = excl;
    base[2 * tid + 1] = excl + p0;
    __syncthreads();
    for (int i = tid; i < BNODES; i += 256) {
        int node = b * BNODES + i;
        int c = cnt[i];
        int pd = (c + 3) & ~3;
        int gb = wbase + base[i];
        if (node < N) rp2[node] = make_int2(gb, pd);
        for (int k = c; k < pd; k++) csr[gb + k] = make_int2(0, 0);
    }
    __syncthreads();
    for (int i = tid; i < BNODES; i += 256) cnt[i] = wbase + base[i];
    __syncthreads();
    for (int i = tid; i < bcnt; i += 256) {
        int2 p = st[i];
        int nl = (p.x >> 17) & (BNODES - 1);
        int pos = atomicAdd(&cnt[nl], 1);
        csr[pos] = make_int2(p.x & 0x1FFFF, p.y);
    }
}

// ---------------- prep: split W into bf16 hi/lo (row-major [n][k]) ----------------
__global__ __launch_bounds__(256) void k_wprep(const float* __restrict__ W1, const float* __restrict__ W2,
                                               unsigned* __restrict__ WH1, unsigned* __restrict__ WL1,
                                               unsigned* __restrict__ WH2, unsigned* __restrict__ WL2) {
    int i = (blockIdx.x & 31) * 256 + threadIdx.x;   // uint index, 8192 per W
    const float* W = (blockIdx.x < 32) ? W1 : W2;
    unsigned* WH = (blockIdx.x < 32) ? WH1 : WH2;
    unsigned* WL = (blockIdx.x < 32) ? WL1 : WL2;
    float a = W[2 * i], b = W[2 * i + 1];
    short ha, la, hb, lb;
    splitf(a, ha, la); splitf(b, hb, lb);
    WH[i] = packsplit_hi(ha, hb);
    WL[i] = packsplit_hi(la, lb);
}

// ---------------- prep: hyperbolic bias vectors ----------------
// HB[layer*65 + lane] = {hb0, hb1}; HB[layer*65+64].x = |hb|^2
__global__ __launch_bounds__(64) void k_bias(const float* __restrict__ B1, const float* __restrict__ B2,
                                             float2* __restrict__ HB) {
    const int lane = threadIdx.x;
    const float* B = (blockIdx.x == 0) ? B1 : B2;
    float2 bb = *(const float2*)(B + 2 * lane);
    float nb2 = wsum(bb.x * bb.x + bb.y * bb.y);
    float nb = fmaxf(sqrtf(nb2), MINN);
    float tbc = fminf(tanh_fast(nb), MAXN);
    float fb = tbc / nb;
    HB[blockIdx.x * 65 + lane] = make_float2(fb * bb.x, fb * bb.y);
    if (lane == 0) HB[blockIdx.x * 65 + 64] = make_float2(tbc * tbc, 0.f);
}

// ---------------- prep: split x into bf16 hi/lo + export norms ----------------
__global__ __launch_bounds__(256) void k_encode(const float* __restrict__ X,
                                                unsigned* __restrict__ XH, unsigned* __restrict__ XL,
                                                float2* __restrict__ NRM, int N) {
    const int lane = threadIdx.x & 63;
    const int wid = threadIdx.x >> 6;
    int row = blockIdx.x * 4 + wid;
    if (row >= N) return;
    float2 u = *(const float2*)(X + (size_t)row * 128 + 2 * lane);
    float n2 = wsum(u.x * u.x + u.y * u.y);
    short h0, l0, h1, l1;
    splitf(u.x, h0, l0); splitf(u.y, h1, l1);
    XH[(size_t)row * 64 + lane] = packsplit_hi(h0, h1);
    XL[(size_t)row * 64 + lane] = packsplit_hi(l0, l1);
    if (lane == 0) {
        float n0 = fmaxf(sqrtf(n2), MINN);
        NRM[row] = make_float2(n0, fminf(n0, ATMAX));
    }
}

// ---------------- fused HypLinear via split-bf16 MFMA (pure fragment loads) ----------------
// one 16-row tile per block; A/B fragments loaded directly from hi/lo buffers.
__global__ __launch_bounds__(256) void k_linear(
    const unsigned* __restrict__ XH, const unsigned* __restrict__ XL,
    const unsigned* __restrict__ WH, const unsigned* __restrict__ WL,
    const float2* __restrict__ HB, const float2* __restrict__ NRM,
    unsigned* __restrict__ OUT, int N)
{
    __shared__ float mxs[16][132];

    const int lane = threadIdx.x & 63;
    const int wid = threadIdx.x >> 6;
    const int lr = lane & 15;
    const int lg = lane >> 4;
    const int row0 = blockIdx.x << 4;

    short8 Bh[2][4], Bl[2][4];
    #pragma unroll
    for (int ct = 0; ct < 2; ct++) {
        const int nrow = wid * 32 + ct * 16 + lr;
        #pragma unroll
        for (int kt = 0; kt < 4; kt++) {
            Bh[ct][kt] = *(const short8*)(WH + nrow * 64 + kt * 16 + lg * 4);
            Bl[ct][kt] = *(const short8*)(WL + nrow * 64 + kt * 16 + lg * 4);
        }
    }
    float2 hb = HB[lane];
    float y2 = HB[64].x;

    const int arow = row0 + lr;
    const bool rv = arow < N;
    short8 Ah[4], Al[4];
    #pragma unroll
    for (int kt = 0; kt < 4; kt++) {
        if (rv) {
            Ah[kt] = *(const short8*)(XH + (size_t)arow * 64 + kt * 16 + lg * 4);
            Al[kt] = *(const short8*)(XL + (size_t)arow * 64 + kt * 16 + lg * 4);
        } else {
            Ah[kt] = short8{0,0,0,0,0,0,0,0};
            Al[kt] = short8{0,0,0,0,0,0,0,0};
        }
    }

    f32x4 acc0 = {0.f, 0.f, 0.f, 0.f}, acc1 = {0.f, 0.f, 0.f, 0.f};
    #pragma unroll
    for (int kt = 0; kt < 4; kt++) {
        acc0 = __builtin_amdgcn_mfma_f32_16x16x32_bf16(Ah[kt], Bh[0][kt], acc0, 0, 0, 0);
        acc1 = __builtin_amdgcn_mfma_f32_16x16x32_bf16(Ah[kt], Bh[1][kt], acc1, 0, 0, 0);
        acc0 = __builtin_amdgcn_mfma_f32_16x16x32_bf16(Al[kt], Bh[0][kt], acc0, 0, 0, 0);
        acc1 = __builtin_amdgcn_mfma_f32_16x16x32_bf16(Al[kt], Bh[1][kt], acc1, 0, 0, 0);
        acc0 = __builtin_amdgcn_mfma_f32_16x16x32_bf16(Ah[kt], Bl[0][kt], acc0, 0, 0, 0);
        acc1 = __builtin_amdgcn_mfma_f32_16x16x32_bf16(Ah[kt], Bl[1][kt], acc1, 0, 0, 0);
    }

    // C/D layout: col = lane&15, row = (lane>>4)*4 + reg
    #pragma unroll
    for (int r = 0; r < 4; r++) {
        mxs[lg * 4 + r][wid * 32 + lr] = acc0[r];
        mxs[lg * 4 + r][wid * 32 + 16 + lr] = acc1[r];
    }
    __syncthreads();

    // epilogue: 4 rows/wave; reduction chains interleaved
    float mn2[4], dmb[4];
    float2 mvv[4];
    #pragma unroll
    for (int r = 0; r < 4; r++) {
        mvv[r] = *(const float2*)&mxs[wid * 4 + r][2 * lane];
        mn2[r] = mvv[r].x * mvv[r].x + mvv[r].y * mvv[r].y;
        dmb[r] = mvv[r].x * hb.x + mvv[r].y * hb.y;
    }
    #pragma unroll
    for (int s = 32; s; s >>= 1) {
        #pragma unroll
        for (int r = 0; r < 4; r++) {
            mn2[r] += __shfl_xor(mn2[r], s, 64);
            dmb[r] += __shfl_xor(dmb[r], s, 64);
        }
    }
    #pragma unroll
    for (int r = 0; r < 4; r++) {
        const int row = row0 + wid * 4 + r;
        if (row < N) {
            float2 nr = NRM[row];
            float xn = fmaxf(nr.x, MINN);
            float axn = nr.y;
            float mxn = fmaxf(sqrtf(mn2[r]), MINN);
            float arg = (mxn / xn) * axn;
            float thc = fminf(tanh_fast(arg), MAXN);
            float f1 = thc / mxn;
            float x2 = thc * thc;
            float xy = f1 * dmb[r];
            float ca = 1.f + 2.f * xy + y2;
            float cb = 1.f - x2;
            float inv = 1.f / fmaxf(1.f + 2.f * xy + x2 * y2, MINN);
            float ng2 = inv * inv * (ca * ca * x2 + 2.f * ca * cb * xy + cb * cb * y2);
            float ng = fmaxf(sqrtf(ng2), MINN);
            float lf = atanh_fast(fminf(ng, MAXN)) / ng;
            float sle = lf * inv;
            float o0 = sle * (ca * f1 * mvv[r].x + cb * hb.x);
            float o1 = sle * (ca * f1 * mvv[r].y + cb * hb.y);
            OUT[(size_t)row * 64 + lane] = pack_bf16(o0, o1);
        }
    }
}

// ---------------- fused aggregation + HypAct ----------------
// last=0: write split-bf16 (hi/lo) + NRM for next layer; last=1: write f32 to OUTF.
__global__ __launch_bounds__(256) void k_aggact(const unsigned* __restrict__ XT, const int2* __restrict__ rp2,
                                                const int2* __restrict__ csr,
                                                float* __restrict__ OUTF,
                                                unsigned* __restrict__ OUTH, unsigned* __restrict__ OUTL,
                                                float2* __restrict__ NRM, int N, int last) {
    const int lane = threadIdx.x & 63;
    const int wid = threadIdx.x >> 6;
    int node = blockIdx.x * 4 + wid;
    if (node >= N) return;
    int2 rr = rp2[node];
    int b = __builtin_amdgcn_readfirstlane(rr.x);
    int cnt = __builtin_amdgcn_readfirstlane(rr.y);
    int e8 = b + (cnt & ~7);

    float ax[8], ay[8];
    #pragma unroll
    for (int j = 0; j < 8; j++) { ax[j] = 0.f; ay[j] = 0.f; }

    for (int i = b; i < e8; i += 8) {
        int2 c[8];
        #pragma unroll
        for (int j = 0; j < 8; j++) c[j] = csr[i + j];
        unsigned v[8];
        #pragma unroll
        for (int j = 0; j < 8; j++) v[j] = XT[(size_t)c[j].x * 64 + lane];
        #pragma unroll
        for (int j = 0; j < 8; j++) {
            float w = __int_as_float(c[j].y);
            ax[j] = fmaf(w, __uint_as_float(v[j] << 16), ax[j]);
            ay[j] = fmaf(w, __uint_as_float(v[j] & 0xffff0000u), ay[j]);
        }
    }
    if (cnt & 4) {
        int i = e8;
        int2 c[4];
        #pragma unroll
        for (int j = 0; j < 4; j++) c[j] = csr[i + j];
        unsigned v[4];
        #pragma unroll
        for (int j = 0; j < 4; j++) v[j] = XT[(size_t)c[j].x * 64 + lane];
        #pragma unroll
        for (int j = 0; j < 4; j++) {
            float w = __int_as_float(c[j].y);
            ax[j] = fmaf(w, __uint_as_float(v[j] << 16), ax[j]);
            ay[j] = fmaf(w, __uint_as_float(v[j] & 0xffff0000u), ay[j]);
        }
    }
    float a0 = ((ax[0] + ax[1]) + (ax[2] + ax[3])) + ((ax[4] + ax[5]) + (ax[6] + ax[7]));
    float a1 = ((ay[0] + ay[1]) + (ay[2] + ay[3])) + ((ay[4] + ay[5]) + (ay[6] + ay[7]));

    // act: logmap0(proj(expmap0(agg))) = agg * min(n,ATMAX)/n
    float r0 = fmaxf(a0, 0.f), r1 = fmaxf(a1, 0.f);
    float n2 = a0 * a0 + a1 * a1;
    float q2 = r0 * r0 + r1 * r1;
    #pragma unroll
    for (int s = 32; s; s >>= 1) {
        n2 += __shfl_xor(n2, s, 64);
        q2 += __shfl_xor(q2, s, 64);
    }
    float n = fmaxf(sqrtf(n2), MINN);
    float cp = fminf(n, ATMAX) / n;
    float nq = fmaxf(cp * sqrtf(q2), MINN);
    float tq = fminf(tanh_fast(nq), MAXN);
    float f2 = tq / nq;
    float sc = f2 * cp;
    float o0 = sc * r0, o1 = sc * r1;
    if (last) {
        *(float2*)(OUTF + (size_t)node * 128 + 2 * lane) = make_float2(o0, o1);
    } else {
        short h0, l0, h1, l1;
        splitf(o0, h0, l0); splitf(o1, h1, l1);
        OUTH[(size_t)node * 64 + lane] = packsplit_hi(h0, h1);
        OUTL[(size_t)node * 64 + lane] = packsplit_hi(l0, l1);
        if (lane == 0) NRM[node] = make_float2(tq, fminf(nq, ATMAX));
    }
}

extern "C" void kernel_launch(void* const* d_in, const int* in_sizes, int n_in,
                              void* d_out, int out_size, void* d_ws, size_t ws_size,
                              hipStream_t stream) {
    const float* x  = (const float*)d_in[0];
    const float* W1 = (const float*)d_in[1];
    const float* b1 = (const float*)d_in[2];
    const float* W2 = (const float*)d_in[3];
    const float* b2 = (const float*)d_in[4];
    const float* ew = (const float*)d_in[5];
    const int* src  = (const int*)d_in[6];
    const int* dst  = (const int*)d_in[7];
    const int N = in_sizes[0] / 128;
    const int E = in_sizes[5];
    float* out = (float*)d_out;

    const int NBUCK = (N + BNODES - 1) >> NBH;
    const int EB = (E + PBE - 1) / PBE;

    char* w = (char*)d_ws;
    unsigned* xt  = (unsigned*)w; w += (size_t)N * 64 * 4;   // bf16 tangent (linear->agg)
    unsigned* xh  = (unsigned*)w; w += (size_t)N * 64 * 4;   // hi input (layer boundary, reused)
    unsigned* xl  = (unsigned*)w; w += (size_t)N * 64 * 4;   // lo input
    int2*   csr   = (int2*)w;   w += (size_t)NBUCK * BWIN * 8;
    float2* nrmA  = (float2*)w; w += (size_t)N * 8;
    float2* nrmB  = (float2*)w; w += (size_t)N * 8;
    int2*   rp2   = (int2*)w;   w += (size_t)N * 8;
    int2*   staging = (int2*)w; w += (size_t)NBUCK * BCAP * 8;
    unsigned* wh1 = (unsigned*)w; w += 8192 * 4;
    unsigned* wl1 = (unsigned*)w; w += 8192 * 4;
    unsigned* wh2 = (unsigned*)w; w += 8192 * 4;
    unsigned* wl2 = (unsigned*)w; w += 8192 * 4;
    float2* hbuf  = (float2*)w; w += 2 * 65 * 8;
    int*    gcur  = (int*)w;    w += (size_t)NBUCK * 4 + 256;

    hipMemsetAsync(gcur, 0, (size_t)NBUCK * 4, stream);
    k_bucket<<<EB, 256, 0, stream>>>(src, dst, ew, gcur, staging, E, NBUCK);
    k_cbuild<<<NBUCK, 256, 0, stream>>>(gcur, staging, csr, rp2, N);
    k_wprep<<<64, 256, 0, stream>>>(W1, W2, wh1, wl1, wh2, wl2);
    k_bias<<<2, 64, 0, stream>>>(b1, b2, hbuf);

    const int rowblocks = (N + 3) / 4;
    const int ntiles = (N + 15) / 16;

    // encode: split raw x + norms
    k_encode<<<rowblocks, 256, 0, stream>>>(x, xh, xl, nrmA, N);
    // layer 1
    k_linear<<<ntiles, 256, 0, stream>>>(xh, xl, wh1, wl1, hbuf, nrmA, xt, N);
    k_aggact<<<rowblocks, 256, 0, stream>>>(xt, rp2, csr, nullptr, xh, xl, nrmB, N, 0);
    // layer 2 (inputs already split by aggact; norms in nrmB)
    k_linear<<<ntiles, 256, 0, stream>>>(xh, xl, wh2, wl2, hbuf + 65, nrmB, xt, N);
    k_aggact<<<rowblocks, 256, 0, stream>>>(xt, rp2, csr, out, nullptr, nullptr, nullptr, N, 1);
}

// Round 11
// 310.309 us; speedup vs baseline: 1.1559x; 1.1559x over previous
//
#include <hip/hip_runtime.h>
#include <hip/hip_bf16.h>

#define MINN 1e-15f
#define MAXN (1.0f - 4e-3f)
#define ATMAX 3.1063031f   // atanhf(1 - 4e-3)

#define NBH 9              // log2(nodes per bucket)
#define BNODES 512
#define BCAP 10240         // staging capacity per bucket
#define BWIN (BCAP + 4 * BNODES)
#define PBE 8192           // edges per pass-B block

typedef short short8 __attribute__((ext_vector_type(8)));
typedef float f32x4 __attribute__((ext_vector_type(4)));

__device__ __forceinline__ float wsum(float v) {
    v += __shfl_xor(v, 32, 64);
    v += __shfl_xor(v, 16, 64);
    v += __shfl_xor(v, 8, 64);
    v += __shfl_xor(v, 4, 64);
    v += __shfl_xor(v, 2, 64);
    v += __shfl_xor(v, 1, 64);
    return v;
}

// truncation split: f ~= bf16(hi) + bf16(lo), combined rel err ~2^-18
__device__ __forceinline__ void splitf(float f, short& hi, short& lo) {
    unsigned u = __float_as_uint(f);
    hi = (short)(u >> 16);
    float r = f - __uint_as_float(u & 0xffff0000u);
    lo = (short)(__float_as_uint(r) >> 16);
}

__device__ __forceinline__ unsigned packsplit_hi(short ha, short hb) {
    return (unsigned)(unsigned short)ha | ((unsigned)(unsigned short)hb << 16);
}

// RNE bf16 pack of two floats
__device__ __forceinline__ unsigned pack_bf16(float a, float b) {
    unsigned ua = __float_as_uint(a);
    unsigned ub = __float_as_uint(b);
    ua = (ua + 0x7fffu + ((ua >> 16) & 1u)) >> 16;
    ub = (ub + 0x7fffu + ((ub >> 16) & 1u)) & 0xffff0000u;
    return ua | ub;
}

// fast transcendentals (args >= 0 in all uses; err ~2e-7)
__device__ __forceinline__ float tanh_fast(float x) {
    float e = __expf(2.f * x);
    return (e - 1.f) * __builtin_amdgcn_rcpf(e + 1.f);
}
__device__ __forceinline__ float atanh_fast(float x) {
    return 0.5f * __logf((1.f + x) * __builtin_amdgcn_rcpf(1.f - x));
}

// ---------------- pass B: bin edges into 512-node buckets ----------------
__global__ __launch_bounds__(256) void k_bucket(const int* __restrict__ src, const int* __restrict__ dst,
                                                const float* __restrict__ ew, int* __restrict__ gcur,
                                                int2* __restrict__ staging, int E, int NBUCK) {
    __shared__ int hist[512];
    const int tid = threadIdx.x;
    const int e0 = blockIdx.x * PBE;
    for (int i = tid; i < 512; i += 256) hist[i] = 0;
    __syncthreads();
    #pragma unroll 4
    for (int j = 0; j < PBE / 256; j++) {
        int e = e0 + j * 256 + tid;
        if (e < E) atomicAdd(&hist[dst[e] >> NBH], 1);
    }
    __syncthreads();
    for (int b = tid; b < NBUCK; b += 256) {
        int c = hist[b];
        hist[b] = c ? atomicAdd(&gcur[b], c) : 0;
    }
    __syncthreads();
    #pragma unroll 4
    for (int j = 0; j < PBE / 256; j++) {
        int e = e0 + j * 256 + tid;
        if (e < E) {
            int d = dst[e];
            int bkt = d >> NBH;
            int pos = atomicAdd(&hist[bkt], 1);
            if (pos < BCAP)
                staging[(size_t)bkt * BCAP + pos] =
                    make_int2((src[e] & 0x1FFFF) | ((d & (BNODES - 1)) << 17), __float_as_int(ew[e]));
        }
    }
}

// ---------------- pass C: per-bucket CSR build ----------------
__global__ __launch_bounds__(256) void k_cbuild(const int* __restrict__ gcur, const int2* __restrict__ staging,
                                                int2* __restrict__ csr, int2* __restrict__ rp2, int N) {
    __shared__ int cnt[BNODES];
    __shared__ int base[BNODES];
    __shared__ int sbuf[256];
    const int tid = threadIdx.x;
    const int b = blockIdx.x;
    const int bcnt = min(gcur[b], BCAP);
    const int wbase = b * BWIN;
    const int2* st = staging + (size_t)b * BCAP;

    for (int i = tid; i < BNODES; i += 256) cnt[i] = 0;
    __syncthreads();
    for (int i = tid; i < bcnt; i += 256) {
        int nl = (st[i].x >> 17) & (BNODES - 1);
        atomicAdd(&cnt[nl], 1);
    }
    __syncthreads();
    int p0 = (cnt[2 * tid] + 3) & ~3;
    int p1 = (cnt[2 * tid + 1] + 3) & ~3;
    int s = p0 + p1;
    sbuf[tid] = s;
    __syncthreads();
    for (int off = 1; off < 256; off <<= 1) {
        int add = (tid >= off) ? sbuf[tid - off] : 0;
        __syncthreads();
        sbuf[tid] += add;
        __syncthreads();
    }
    int excl = sbuf[tid] - s;
    base[2 * tid] = excl;
    base[2 * tid + 1] = excl + p0;
    __syncthreads();
    for (int i = tid; i < BNODES; i += 256) {
        int node = b * BNODES + i;
        int c = cnt[i];
        int pd = (c + 3) & ~3;
        int gb = wbase + base[i];
        if (node < N) rp2[node] = make_int2(gb, pd);
        for (int k = c; k < pd; k++) csr[gb + k] = make_int2(0, 0);
    }
    __syncthreads();
    for (int i = tid; i < BNODES; i += 256) cnt[i] = wbase + base[i];
    __syncthreads();
    for (int i = tid; i < bcnt; i += 256) {
        int2 p = st[i];
        int nl = (p.x >> 17) & (BNODES - 1);
        int pos = atomicAdd(&cnt[nl], 1);
        csr[pos] = make_int2(p.x & 0x1FFFF, p.y);
    }
}

// ---------------- prep: split W into bf16 hi/lo (row-major [n][k]) ----------------
__global__ __launch_bounds__(256) void k_wprep(const float* __restrict__ W1, const float* __restrict__ W2,
                                               unsigned* __restrict__ WH1, unsigned* __restrict__ WL1,
                                               unsigned* __restrict__ WH2, unsigned* __restrict__ WL2) {
    int i = (blockIdx.x & 31) * 256 + threadIdx.x;
    const float* W = (blockIdx.x < 32) ? W1 : W2;
    unsigned* WH = (blockIdx.x < 32) ? WH1 : WH2;
    unsigned* WL = (blockIdx.x < 32) ? WL1 : WL2;
    float a = W[2 * i], b = W[2 * i + 1];
    short ha, la, hb, lb;
    splitf(a, ha, la); splitf(b, hb, lb);
    WH[i] = packsplit_hi(ha, hb);
    WL[i] = packsplit_hi(la, lb);
}

// ---------------- prep: hyperbolic bias vectors ----------------
__global__ __launch_bounds__(64) void k_bias(const float* __restrict__ B1, const float* __restrict__ B2,
                                             float2* __restrict__ HB) {
    const int lane = threadIdx.x;
    const float* B = (blockIdx.x == 0) ? B1 : B2;
    float2 bb = *(const float2*)(B + 2 * lane);
    float nb2 = wsum(bb.x * bb.x + bb.y * bb.y);
    float nb = fmaxf(sqrtf(nb2), MINN);
    float tbc = fminf(tanh_fast(nb), MAXN);
    float fb = tbc / nb;
    HB[blockIdx.x * 65 + lane] = make_float2(fb * bb.x, fb * bb.y);
    if (lane == 0) HB[blockIdx.x * 65 + 64] = make_float2(tbc * tbc, 0.f);
}

// ---------------- fused HypLinear: 4 row-tiles (64 rows) per block ----------------
// ENCODE=1: read f32 X, split in-register, compute input norms in-kernel.
// ENCODE=0: read pre-split XH/XL; norms from NRM (written by aggact).
template <int ENCODE>
__global__ __launch_bounds__(256) void k_linear(
    const float* __restrict__ X,
    const unsigned* __restrict__ XH, const unsigned* __restrict__ XL,
    const unsigned* __restrict__ WH, const unsigned* __restrict__ WL,
    const float2* __restrict__ HB, const float2* __restrict__ NRM,
    unsigned* __restrict__ OUT, int N)
{
    __shared__ float mxs[4][16][132];
    __shared__ float xn2s[4][16];

    const int lane = threadIdx.x & 63;
    const int wid = threadIdx.x >> 6;
    const int lr = lane & 15;
    const int lg = lane >> 4;
    const int tbase = blockIdx.x * 4;

    // B fragments: wave owns cols [wid*32, wid*32+32)
    short8 Bh[2][4], Bl[2][4];
    #pragma unroll
    for (int ct = 0; ct < 2; ct++) {
        const int nrow = wid * 32 + ct * 16 + lr;
        #pragma unroll
        for (int kt = 0; kt < 4; kt++) {
            Bh[ct][kt] = *(const short8*)(WH + nrow * 64 + kt * 16 + lg * 4);
            Bl[ct][kt] = *(const short8*)(WL + nrow * 64 + kt * 16 + lg * 4);
        }
    }
    float2 hb = HB[lane];
    float y2 = HB[64].x;

    // MFMA phase: 4 tiles, accs dumped to per-tile LDS regions, single barrier after
    #pragma unroll
    for (int t = 0; t < 4; t++) {
        const int row0 = (tbase + t) << 4;
        if (row0 >= N) break;
        const int arow = min(row0 + lr, N - 1);

        short8 Ah[4], Al[4];
        if (ENCODE) {
            float xn2 = 0.f;
            const float* xr = X + (size_t)arow * 128 + lg * 8;
            #pragma unroll
            for (int kt = 0; kt < 4; kt++) {
                float4 a0 = *(const float4*)(xr + kt * 32);
                float4 a1 = *(const float4*)(xr + kt * 32 + 4);
                float av[8] = {a0.x, a0.y, a0.z, a0.w, a1.x, a1.y, a1.z, a1.w};
                #pragma unroll
                for (int i = 0; i < 8; i++) {
                    xn2 = fmaf(av[i], av[i], xn2);
                    short h, l; splitf(av[i], h, l);
                    Ah[kt][i] = h; Al[kt][i] = l;
                }
            }
            xn2 += __shfl_xor(xn2, 16, 64);
            xn2 += __shfl_xor(xn2, 32, 64);
            if (wid == 0 && lane < 16) xn2s[t][lane] = xn2;
        } else {
            #pragma unroll
            for (int kt = 0; kt < 4; kt++) {
                Ah[kt] = *(const short8*)(XH + (size_t)arow * 64 + kt * 16 + lg * 4);
                Al[kt] = *(const short8*)(XL + (size_t)arow * 64 + kt * 16 + lg * 4);
            }
        }

        f32x4 acc0 = {0.f, 0.f, 0.f, 0.f}, acc1 = {0.f, 0.f, 0.f, 0.f};
        #pragma unroll
        for (int kt = 0; kt < 4; kt++) {
            acc0 = __builtin_amdgcn_mfma_f32_16x16x32_bf16(Ah[kt], Bh[0][kt], acc0, 0, 0, 0);
            acc1 = __builtin_amdgcn_mfma_f32_16x16x32_bf16(Ah[kt], Bh[1][kt], acc1, 0, 0, 0);
            acc0 = __builtin_amdgcn_mfma_f32_16x16x32_bf16(Al[kt], Bh[0][kt], acc0, 0, 0, 0);
            acc1 = __builtin_amdgcn_mfma_f32_16x16x32_bf16(Al[kt], Bh[1][kt], acc1, 0, 0, 0);
            acc0 = __builtin_amdgcn_mfma_f32_16x16x32_bf16(Ah[kt], Bl[0][kt], acc0, 0, 0, 0);
            acc1 = __builtin_amdgcn_mfma_f32_16x16x32_bf16(Ah[kt], Bl[1][kt], acc1, 0, 0, 0);
        }

        // C/D layout: col = lane&15, row = (lane>>4)*4 + reg
        #pragma unroll
        for (int r = 0; r < 4; r++) {
            mxs[t][lg * 4 + r][wid * 32 + lr] = acc0[r];
            mxs[t][lg * 4 + r][wid * 32 + 16 + lr] = acc1[r];
        }
    }
    __syncthreads();

    // epilogue: 16 rows/wave (4 per tile), all 32 reduction chains interleaved
    float mn2[16], dmb[16];
    float2 mvv[16];
    #pragma unroll
    for (int t = 0; t < 4; t++) {
        #pragma unroll
        for (int r = 0; r < 4; r++) {
            const int q = t * 4 + r;
            mvv[q] = *(const float2*)&mxs[t][wid * 4 + r][2 * lane];
            mn2[q] = mvv[q].x * mvv[q].x + mvv[q].y * mvv[q].y;
            dmb[q] = mvv[q].x * hb.x + mvv[q].y * hb.y;
        }
    }
    #pragma unroll
    for (int s = 32; s; s >>= 1) {
        #pragma unroll
        for (int q = 0; q < 16; q++) {
            mn2[q] += __shfl_xor(mn2[q], s, 64);
            dmb[q] += __shfl_xor(dmb[q], s, 64);
        }
    }
    #pragma unroll
    for (int t = 0; t < 4; t++) {
        #pragma unroll
        for (int r = 0; r < 4; r++) {
            const int q = t * 4 + r;
            const int row = ((tbase + t) << 4) + wid * 4 + r;
            if (row < N) {
                float xn, axn;
                if (ENCODE) {
                    float n0 = fmaxf(sqrtf(xn2s[t][wid * 4 + r]), MINN);
                    xn = n0;
                    axn = fminf(n0, ATMAX);
                } else {
                    float2 nr = NRM[row];
                    xn = fmaxf(nr.x, MINN);
                    axn = nr.y;
                }
                float mxn = fmaxf(sqrtf(mn2[q]), MINN);
                float arg = (mxn / xn) * axn;
                float thc = fminf(tanh_fast(arg), MAXN);
                float f1 = thc / mxn;
                float x2 = thc * thc;
                float xy = f1 * dmb[q];
                float ca = 1.f + 2.f * xy + y2;
                float cb = 1.f - x2;
                float inv = 1.f / fmaxf(1.f + 2.f * xy + x2 * y2, MINN);
                float ng2 = inv * inv * (ca * ca * x2 + 2.f * ca * cb * xy + cb * cb * y2);
                float ng = fmaxf(sqrtf(ng2), MINN);
                float lf = atanh_fast(fminf(ng, MAXN)) / ng;
                float sle = lf * inv;
                float o0 = sle * (ca * f1 * mvv[q].x + cb * hb.x);
                float o1 = sle * (ca * f1 * mvv[q].y + cb * hb.y);
                OUT[(size_t)row * 64 + lane] = pack_bf16(o0, o1);
            }
        }
    }
}

// ---------------- fused aggregation + HypAct ----------------
__global__ __launch_bounds__(256) void k_aggact(const unsigned* __restrict__ XT, const int2* __restrict__ rp2,
                                                const int2* __restrict__ csr,
                                                float* __restrict__ OUTF,
                                                unsigned* __restrict__ OUTH, unsigned* __restrict__ OUTL,
                                                float2* __restrict__ NRM, int N, int last) {
    const int lane = threadIdx.x & 63;
    const int wid = threadIdx.x >> 6;
    int node = blockIdx.x * 4 + wid;
    if (node >= N) return;
    int2 rr = rp2[node];
    int b = __builtin_amdgcn_readfirstlane(rr.x);
    int cnt = __builtin_amdgcn_readfirstlane(rr.y);
    int e8 = b + (cnt & ~7);

    float ax[8], ay[8];
    #pragma unroll
    for (int j = 0; j < 8; j++) { ax[j] = 0.f; ay[j] = 0.f; }

    for (int i = b; i < e8; i += 8) {
        int2 c[8];
        #pragma unroll
        for (int j = 0; j < 8; j++) c[j] = csr[i + j];
        unsigned v[8];
        #pragma unroll
        for (int j = 0; j < 8; j++) v[j] = XT[(size_t)c[j].x * 64 + lane];
        #pragma unroll
        for (int j = 0; j < 8; j++) {
            float w = __int_as_float(c[j].y);
            ax[j] = fmaf(w, __uint_as_float(v[j] << 16), ax[j]);
            ay[j] = fmaf(w, __uint_as_float(v[j] & 0xffff0000u), ay[j]);
        }
    }
    if (cnt & 4) {
        int i = e8;
        int2 c[4];
        #pragma unroll
        for (int j = 0; j < 4; j++) c[j] = csr[i + j];
        unsigned v[4];
        #pragma unroll
        for (int j = 0; j < 4; j++) v[j] = XT[(size_t)c[j].x * 64 + lane];
        #pragma unroll
        for (int j = 0; j < 4; j++) {
            float w = __int_as_float(c[j].y);
            ax[j] = fmaf(w, __uint_as_float(v[j] << 16), ax[j]);
            ay[j] = fmaf(w, __uint_as_float(v[j] & 0xffff0000u), ay[j]);
        }
    }
    float a0 = ((ax[0] + ax[1]) + (ax[2] + ax[3])) + ((ax[4] + ax[5]) + (ax[6] + ax[7]));
    float a1 = ((ay[0] + ay[1]) + (ay[2] + ay[3])) + ((ay[4] + ay[5]) + (ay[6] + ay[7]));

    // act: logmap0(proj(expmap0(agg))) = agg * min(n,ATMAX)/n
    float r0 = fmaxf(a0, 0.f), r1 = fmaxf(a1, 0.f);
    float n2 = a0 * a0 + a1 * a1;
    float q2 = r0 * r0 + r1 * r1;
    #pragma unroll
    for (int s = 32; s; s >>= 1) {
        n2 += __shfl_xor(n2, s, 64);
        q2 += __shfl_xor(q2, s, 64);
    }
    float n = fmaxf(sqrtf(n2), MINN);
    float cp = fminf(n, ATMAX) / n;
    float nq = fmaxf(cp * sqrtf(q2), MINN);
    float tq = fminf(tanh_fast(nq), MAXN);
    float f2 = tq / nq;
    float sc = f2 * cp;
    float o0 = sc * r0, o1 = sc * r1;
    if (last) {
        *(float2*)(OUTF + (size_t)node * 128 + 2 * lane) = make_float2(o0, o1);
    } else {
        short h0, l0, h1, l1;
        splitf(o0, h0, l0); splitf(o1, h1, l1);
        OUTH[(size_t)node * 64 + lane] = packsplit_hi(h0, h1);
        OUTL[(size_t)node * 64 + lane] = packsplit_hi(l0, l1);
        if (lane == 0) NRM[node] = make_float2(tq, fminf(nq, ATMAX));
    }
}

extern "C" void kernel_launch(void* const* d_in, const int* in_sizes, int n_in,
                              void* d_out, int out_size, void* d_ws, size_t ws_size,
                              hipStream_t stream) {
    const float* x  = (const float*)d_in[0];
    const float* W1 = (const float*)d_in[1];
    const float* b1 = (const float*)d_in[2];
    const float* W2 = (const float*)d_in[3];
    const float* b2 = (const float*)d_in[4];
    const float* ew = (const float*)d_in[5];
    const int* src  = (const int*)d_in[6];
    const int* dst  = (const int*)d_in[7];
    const int N = in_sizes[0] / 128;
    const int E = in_sizes[5];
    float* out = (float*)d_out;

    const int NBUCK = (N + BNODES - 1) >> NBH;
    const int EB = (E + PBE - 1) / PBE;

    char* w = (char*)d_ws;
    unsigned* xt  = (unsigned*)w; w += (size_t)N * 64 * 4;   // bf16 tangent (linear->agg)
    unsigned* xh  = (unsigned*)w; w += (size_t)N * 64 * 4;   // hi (aggact L1 -> linear L2)
    unsigned* xl  = (unsigned*)w; w += (size_t)N * 64 * 4;   // lo
    int2*   csr   = (int2*)w;   w += (size_t)NBUCK * BWIN * 8;
    float2* nrm   = (float2*)w; w += (size_t)N * 8;
    int2*   rp2   = (int2*)w;   w += (size_t)N * 8;
    int2*   staging = (int2*)w; w += (size_t)NBUCK * BCAP * 8;
    unsigned* wh1 = (unsigned*)w; w += 8192 * 4;
    unsigned* wl1 = (unsigned*)w; w += 8192 * 4;
    unsigned* wh2 = (unsigned*)w; w += 8192 * 4;
    unsigned* wl2 = (unsigned*)w; w += 8192 * 4;
    float2* hbuf  = (float2*)w; w += 2 * 65 * 8;
    int*    gcur  = (int*)w;    w += (size_t)NBUCK * 4 + 256;

    hipMemsetAsync(gcur, 0, (size_t)NBUCK * 4, stream);
    k_bucket<<<EB, 256, 0, stream>>>(src, dst, ew, gcur, staging, E, NBUCK);
    k_cbuild<<<NBUCK, 256, 0, stream>>>(gcur, staging, csr, rp2, N);
    k_wprep<<<64, 256, 0, stream>>>(W1, W2, wh1, wl1, wh2, wl2);
    k_bias<<<2, 64, 0, stream>>>(b1, b2, hbuf);

    const int rowblocks = (N + 3) / 4;
    const int ntiles = (N + 15) / 16;
    const int nlb = (ntiles + 3) / 4;

    // layer 1 (encode fused: reads f32 x directly)
    k_linear<1><<<nlb, 256, 0, stream>>>(x, nullptr, nullptr, wh1, wl1, hbuf, nullptr, xt, N);
    k_aggact<<<rowblocks, 256, 0, stream>>>(xt, rp2, csr, nullptr, xh, xl, nrm, N, 0);
    // layer 2 (pre-split inputs from aggact; norms in nrm)
    k_linear<0><<<nlb, 256, 0, stream>>>(nullptr, xh, xl, wh2, wl2, hbuf + 65, nrm, xt, N);
    k_aggact<<<rowblocks, 256, 0, stream>>>(xt, rp2, csr, out, nullptr, nullptr, nullptr, N, 1);
}

// Round 12
// 300.950 us; speedup vs baseline: 1.1918x; 1.0311x over previous
//
#include <hip/hip_runtime.h>
#include <hip/hip_bf16.h>

#define MINN 1e-15f
#define MAXN (1.0f - 4e-3f)
#define ATMAX 3.1063031f   // atanhf(1 - 4e-3)

#define NBH 9              // log2(nodes per bucket)
#define BNODES 512
#define BCAP 10240         // staging capacity per bucket
#define BWIN (BCAP + 4 * BNODES)
#define PBE 8192           // edges per pass-B block

typedef short short8 __attribute__((ext_vector_type(8)));
typedef float f32x4 __attribute__((ext_vector_type(4)));

__device__ __forceinline__ float wsum(float v) {
    v += __shfl_xor(v, 32, 64);
    v += __shfl_xor(v, 16, 64);
    v += __shfl_xor(v, 8, 64);
    v += __shfl_xor(v, 4, 64);
    v += __shfl_xor(v, 2, 64);
    v += __shfl_xor(v, 1, 64);
    return v;
}

// truncation split: f ~= bf16(hi) + bf16(lo), combined rel err ~2^-18
__device__ __forceinline__ void splitf(float f, short& hi, short& lo) {
    unsigned u = __float_as_uint(f);
    hi = (short)(u >> 16);
    float r = f - __uint_as_float(u & 0xffff0000u);
    lo = (short)(__float_as_uint(r) >> 16);
}

__device__ __forceinline__ unsigned packsplit_hi(short ha, short hb) {
    return (unsigned)(unsigned short)ha | ((unsigned)(unsigned short)hb << 16);
}

// RNE bf16 pack of two floats
__device__ __forceinline__ unsigned pack_bf16(float a, float b) {
    unsigned ua = __float_as_uint(a);
    unsigned ub = __float_as_uint(b);
    ua = (ua + 0x7fffu + ((ua >> 16) & 1u)) >> 16;
    ub = (ub + 0x7fffu + ((ub >> 16) & 1u)) & 0xffff0000u;
    return ua | ub;
}

// fast transcendentals (args >= 0 in all uses; err ~2e-7)
__device__ __forceinline__ float tanh_fast(float x) {
    float e = __expf(2.f * x);
    return (e - 1.f) * __builtin_amdgcn_rcpf(e + 1.f);
}
__device__ __forceinline__ float atanh_fast(float x) {
    return 0.5f * __logf((1.f + x) * __builtin_amdgcn_rcpf(1.f - x));
}

// ---------------- pass B: bin edges into 512-node buckets ----------------
__global__ __launch_bounds__(256) void k_bucket(const int* __restrict__ src, const int* __restrict__ dst,
                                                const float* __restrict__ ew, int* __restrict__ gcur,
                                                int2* __restrict__ staging, int E, int NBUCK) {
    __shared__ int hist[512];
    const int tid = threadIdx.x;
    const int e0 = blockIdx.x * PBE;
    for (int i = tid; i < 512; i += 256) hist[i] = 0;
    __syncthreads();
    #pragma unroll 4
    for (int j = 0; j < PBE / 256; j++) {
        int e = e0 + j * 256 + tid;
        if (e < E) atomicAdd(&hist[dst[e] >> NBH], 1);
    }
    __syncthreads();
    for (int b = tid; b < NBUCK; b += 256) {
        int c = hist[b];
        hist[b] = c ? atomicAdd(&gcur[b], c) : 0;
    }
    __syncthreads();
    #pragma unroll 4
    for (int j = 0; j < PBE / 256; j++) {
        int e = e0 + j * 256 + tid;
        if (e < E) {
            int d = dst[e];
            int bkt = d >> NBH;
            int pos = atomicAdd(&hist[bkt], 1);
            if (pos < BCAP)
                staging[(size_t)bkt * BCAP + pos] =
                    make_int2((src[e] & 0x1FFFF) | ((d & (BNODES - 1)) << 17), __float_as_int(ew[e]));
        }
    }
}

// ---------------- pass C: per-bucket CSR build ----------------
__global__ __launch_bounds__(256) void k_cbuild(const int* __restrict__ gcur, const int2* __restrict__ staging,
                                                int2* __restrict__ csr, int2* __restrict__ rp2, int N) {
    __shared__ int cnt[BNODES];
    __shared__ int base[BNODES];
    __shared__ int sbuf[256];
    const int tid = threadIdx.x;
    const int b = blockIdx.x;
    const int bcnt = min(gcur[b], BCAP);
    const int wbase = b * BWIN;
    const int2* st = staging + (size_t)b * BCAP;

    for (int i = tid; i < BNODES; i += 256) cnt[i] = 0;
    __syncthreads();
    for (int i = tid; i < bcnt; i += 256) {
        int nl = (st[i].x >> 17) & (BNODES - 1);
        atomicAdd(&cnt[nl], 1);
    }
    __syncthreads();
    int p0 = (cnt[2 * tid] + 3) & ~3;
    int p1 = (cnt[2 * tid + 1] + 3) & ~3;
    int s = p0 + p1;
    sbuf[tid] = s;
    __syncthreads();
    for (int off = 1; off < 256; off <<= 1) {
        int add = (tid >= off) ? sbuf[tid - off] : 0;
        __syncthreads();
        sbuf[tid] += add;
        __syncthreads();
    }
    int excl = sbuf[tid] - s;
    base[2 * tid] = excl;
    base[2 * tid + 1] = excl + p0;
    __syncthreads();
    for (int i = tid; i < BNODES; i += 256) {
        int node = b * BNODES + i;
        int c = cnt[i];
        int pd = (c + 3) & ~3;
        int gb = wbase + base[i];
        if (node < N) rp2[node] = make_int2(gb, pd);
        for (int k = c; k < pd; k++) csr[gb + k] = make_int2(0, 0);
    }
    __syncthreads();
    for (int i = tid; i < BNODES; i += 256) cnt[i] = wbase + base[i];
    __syncthreads();
    for (int i = tid; i < bcnt; i += 256) {
        int2 p = st[i];
        int nl = (p.x >> 17) & (BNODES - 1);
        int pos = atomicAdd(&cnt[nl], 1);
        csr[pos] = make_int2(p.x & 0x1FFFF, p.y);
    }
}

// ---------------- prep: split W into bf16 hi/lo (row-major [n][k]) ----------------
__global__ __launch_bounds__(256) void k_wprep(const float* __restrict__ W1, const float* __restrict__ W2,
                                               unsigned* __restrict__ WH1, unsigned* __restrict__ WL1,
                                               unsigned* __restrict__ WH2, unsigned* __restrict__ WL2) {
    int i = (blockIdx.x & 31) * 256 + threadIdx.x;
    const float* W = (blockIdx.x < 32) ? W1 : W2;
    unsigned* WH = (blockIdx.x < 32) ? WH1 : WH2;
    unsigned* WL = (blockIdx.x < 32) ? WL1 : WL2;
    float a = W[2 * i], b = W[2 * i + 1];
    short ha, la, hb, lb;
    splitf(a, ha, la); splitf(b, hb, lb);
    WH[i] = packsplit_hi(ha, hb);
    WL[i] = packsplit_hi(la, lb);
}

// ---------------- prep: hyperbolic bias vectors ----------------
__global__ __launch_bounds__(64) void k_bias(const float* __restrict__ B1, const float* __restrict__ B2,
                                             float2* __restrict__ HB) {
    const int lane = threadIdx.x;
    const float* B = (blockIdx.x == 0) ? B1 : B2;
    float2 bb = *(const float2*)(B + 2 * lane);
    float nb2 = wsum(bb.x * bb.x + bb.y * bb.y);
    float nb = fmaxf(sqrtf(nb2), MINN);
    float tbc = fminf(tanh_fast(nb), MAXN);
    float fb = tbc / nb;
    HB[blockIdx.x * 65 + lane] = make_float2(fb * bb.x, fb * bb.y);
    if (lane == 0) HB[blockIdx.x * 65 + 64] = make_float2(tbc * tbc, 0.f);
}

// ---------------- fused HypLinear: direct-store epilogue, no LDS tile ----------------
// Wave owns cols [wid*32, wid*32+32); tile ct covers interleaved cols wid*32+2*lr+ct,
// so a lane's (acc0[r], acc1[r]) is the adjacent pair (2c, 2c+1) -> direct bf16 pack+store.
// Row reductions: per-lane partials + 4-step intra-group shfl; 2KB LDS for cross-wave sums.
// Scalar chain computed once per row (lane lr), broadcast via width-16 shfl.
template <int ENCODE>
__global__ __launch_bounds__(256) void k_linear(
    const float* __restrict__ X,
    const unsigned* __restrict__ XH, const unsigned* __restrict__ XL,
    const unsigned* __restrict__ WH, const unsigned* __restrict__ WL,
    const float2* __restrict__ HB, const float2* __restrict__ NRM,
    unsigned* __restrict__ OUT, int N)
{
    __shared__ float pmn[4][16][4];
    __shared__ float pdm[4][16][4];

    const int lane = threadIdx.x & 63;
    const int wid = threadIdx.x >> 6;
    const int lr = lane & 15;
    const int lg = lane >> 4;
    const int tbase = blockIdx.x * 4;

    // B fragments: tile ct = cols wid*32 + 2*lr + ct (even/odd interleave)
    short8 Bh[2][4], Bl[2][4];
    #pragma unroll
    for (int ct = 0; ct < 2; ct++) {
        const int nrow = wid * 32 + 2 * lr + ct;
        #pragma unroll
        for (int kt = 0; kt < 4; kt++) {
            Bh[ct][kt] = *(const short8*)(WH + nrow * 64 + kt * 16 + lg * 4);
            Bl[ct][kt] = *(const short8*)(WL + nrow * 64 + kt * 16 + lg * 4);
        }
    }
    const float2 hbc = HB[wid * 16 + lr];   // hb elems (2c, 2c+1) for c = wid*16+lr
    const float y2 = HB[64].x;

    f32x4 acc[4][2];
    float xnr[4];

    #pragma unroll
    for (int t = 0; t < 4; t++) {
        const int row0 = (tbase + t) << 4;
        if (row0 >= N) break;
        const int arow = min(row0 + lr, N - 1);

        short8 Ah[4], Al[4];
        if (ENCODE) {
            float xn2 = 0.f;
            const float* xr = X + (size_t)arow * 128 + lg * 8;
            #pragma unroll
            for (int kt = 0; kt < 4; kt++) {
                float4 a0 = *(const float4*)(xr + kt * 32);
                float4 a1 = *(const float4*)(xr + kt * 32 + 4);
                float av[8] = {a0.x, a0.y, a0.z, a0.w, a1.x, a1.y, a1.z, a1.w};
                #pragma unroll
                for (int i = 0; i < 8; i++) {
                    xn2 = fmaf(av[i], av[i], xn2);
                    short h, l; splitf(av[i], h, l);
                    Ah[kt][i] = h; Al[kt][i] = l;
                }
            }
            xn2 += __shfl_xor(xn2, 16, 64);
            xn2 += __shfl_xor(xn2, 32, 64);
            xnr[t] = xn2;   // norm^2 of row row0+lr
        } else {
            #pragma unroll
            for (int kt = 0; kt < 4; kt++) {
                Ah[kt] = *(const short8*)(XH + (size_t)arow * 64 + kt * 16 + lg * 4);
                Al[kt] = *(const short8*)(XL + (size_t)arow * 64 + kt * 16 + lg * 4);
            }
        }

        f32x4 a0 = {0.f, 0.f, 0.f, 0.f}, a1 = {0.f, 0.f, 0.f, 0.f};
        #pragma unroll
        for (int kt = 0; kt < 4; kt++) {
            a0 = __builtin_amdgcn_mfma_f32_16x16x32_bf16(Ah[kt], Bh[0][kt], a0, 0, 0, 0);
            a1 = __builtin_amdgcn_mfma_f32_16x16x32_bf16(Ah[kt], Bh[1][kt], a1, 0, 0, 0);
            a0 = __builtin_amdgcn_mfma_f32_16x16x32_bf16(Al[kt], Bh[0][kt], a0, 0, 0, 0);
            a1 = __builtin_amdgcn_mfma_f32_16x16x32_bf16(Al[kt], Bh[1][kt], a1, 0, 0, 0);
            a0 = __builtin_amdgcn_mfma_f32_16x16x32_bf16(Ah[kt], Bl[0][kt], a0, 0, 0, 0);
            a1 = __builtin_amdgcn_mfma_f32_16x16x32_bf16(Ah[kt], Bl[1][kt], a1, 0, 0, 0);
        }
        acc[t][0] = a0; acc[t][1] = a1;

        // per-row partials over this wave's 32 cols; C row = lg*4 + r
        float pm[4], pd[4];
        #pragma unroll
        for (int r = 0; r < 4; r++) {
            pm[r] = a0[r] * a0[r] + a1[r] * a1[r];
            pd[r] = a0[r] * hbc.x + a1[r] * hbc.y;
        }
        #pragma unroll
        for (int s = 1; s <= 8; s <<= 1) {
            #pragma unroll
            for (int r = 0; r < 4; r++) {
                pm[r] += __shfl_xor(pm[r], s, 64);
                pd[r] += __shfl_xor(pd[r], s, 64);
            }
        }
        if (lr == 0) {
            #pragma unroll
            for (int r = 0; r < 4; r++) {
                pmn[t][lg * 4 + r][wid] = pm[r];
                pdm[t][lg * 4 + r][wid] = pd[r];
            }
        }
    }
    __syncthreads();

    #pragma unroll
    for (int t = 0; t < 4; t++) {
        const int row0 = (tbase + t) << 4;
        if (row0 >= N) break;

        // chain for row row0+lr (computed by all 4 lg groups redundantly)
        float4 qm = *(const float4*)pmn[t][lr];
        float4 qd = *(const float4*)pdm[t][lr];
        float mn2 = (qm.x + qm.y) + (qm.z + qm.w);
        float dmb = (qd.x + qd.y) + (qd.z + qd.w);
        const int crow = row0 + lr;
        float caf1 = 0.f, cbs = 0.f;
        if (crow < N) {
            float xn, axn;
            if (ENCODE) {
                float n0 = fmaxf(sqrtf(xnr[t]), MINN);
                xn = n0;
                axn = fminf(n0, ATMAX);
            } else {
                float2 nr = NRM[crow];
                xn = fmaxf(nr.x, MINN);
                axn = nr.y;
            }
            float mxn = fmaxf(sqrtf(mn2), MINN);
            float arg = (mxn / xn) * axn;
            float thc = fminf(tanh_fast(arg), MAXN);
            float f1 = thc / mxn;
            float x2 = thc * thc;
            float xy = f1 * dmb;
            float ca = 1.f + 2.f * xy + y2;
            float cb = 1.f - x2;
            float inv = 1.f / fmaxf(1.f + 2.f * xy + x2 * y2, MINN);
            float ng2 = inv * inv * (ca * ca * x2 + 2.f * ca * cb * xy + cb * cb * y2);
            float ng = fmaxf(sqrtf(ng2), MINN);
            float lf = atanh_fast(fminf(ng, MAXN)) / ng;
            float sle = lf * inv;
            caf1 = sle * ca * f1;
            cbs = sle * cb;
        }
        #pragma unroll
        for (int r = 0; r < 4; r++) {
            const int q = lg * 4 + r;
            float c1 = __shfl(caf1, q, 16);
            float c2 = __shfl(cbs, q, 16);
            const int row = row0 + q;
            if (row < N) {
                float o0 = c1 * acc[t][0][r] + c2 * hbc.x;
                float o1 = c1 * acc[t][1][r] + c2 * hbc.y;
                OUT[(size_t)row * 64 + wid * 16 + lr] = pack_bf16(o0, o1);
            }
        }
    }
}

// ---------------- fused aggregation + HypAct ----------------
__global__ __launch_bounds__(256) void k_aggact(const unsigned* __restrict__ XT, const int2* __restrict__ rp2,
                                                const int2* __restrict__ csr,
                                                float* __restrict__ OUTF,
                                                unsigned* __restrict__ OUTH, unsigned* __restrict__ OUTL,
                                                float2* __restrict__ NRM, int N, int last) {
    const int lane = threadIdx.x & 63;
    const int wid = threadIdx.x >> 6;
    int node = blockIdx.x * 4 + wid;
    if (node >= N) return;
    int2 rr = rp2[node];
    int b = __builtin_amdgcn_readfirstlane(rr.x);
    int cnt = __builtin_amdgcn_readfirstlane(rr.y);
    int e8 = b + (cnt & ~7);

    float ax[8], ay[8];
    #pragma unroll
    for (int j = 0; j < 8; j++) { ax[j] = 0.f; ay[j] = 0.f; }

    for (int i = b; i < e8; i += 8) {
        int2 c[8];
        #pragma unroll
        for (int j = 0; j < 8; j++) c[j] = csr[i + j];
        unsigned v[8];
        #pragma unroll
        for (int j = 0; j < 8; j++) v[j] = XT[(size_t)c[j].x * 64 + lane];
        #pragma unroll
        for (int j = 0; j < 8; j++) {
            float w = __int_as_float(c[j].y);
            ax[j] = fmaf(w, __uint_as_float(v[j] << 16), ax[j]);
            ay[j] = fmaf(w, __uint_as_float(v[j] & 0xffff0000u), ay[j]);
        }
    }
    if (cnt & 4) {
        int i = e8;
        int2 c[4];
        #pragma unroll
        for (int j = 0; j < 4; j++) c[j] = csr[i + j];
        unsigned v[4];
        #pragma unroll
        for (int j = 0; j < 4; j++) v[j] = XT[(size_t)c[j].x * 64 + lane];
        #pragma unroll
        for (int j = 0; j < 4; j++) {
            float w = __int_as_float(c[j].y);
            ax[j] = fmaf(w, __uint_as_float(v[j] << 16), ax[j]);
            ay[j] = fmaf(w, __uint_as_float(v[j] & 0xffff0000u), ay[j]);
        }
    }
    float a0 = ((ax[0] + ax[1]) + (ax[2] + ax[3])) + ((ax[4] + ax[5]) + (ax[6] + ax[7]));
    float a1 = ((ay[0] + ay[1]) + (ay[2] + ay[3])) + ((ay[4] + ay[5]) + (ay[6] + ay[7]));

    // act: logmap0(proj(expmap0(agg))) = agg * min(n,ATMAX)/n
    float r0 = fmaxf(a0, 0.f), r1 = fmaxf(a1, 0.f);
    float n2 = a0 * a0 + a1 * a1;
    float q2 = r0 * r0 + r1 * r1;
    #pragma unroll
    for (int s = 32; s; s >>= 1) {
        n2 += __shfl_xor(n2, s, 64);
        q2 += __shfl_xor(q2, s, 64);
    }
    float n = fmaxf(sqrtf(n2), MINN);
    float cp = fminf(n, ATMAX) / n;
    float nq = fmaxf(cp * sqrtf(q2), MINN);
    float tq = fminf(tanh_fast(nq), MAXN);
    float f2 = tq / nq;
    float sc = f2 * cp;
    float o0 = sc * r0, o1 = sc * r1;
    if (last) {
        *(float2*)(OUTF + (size_t)node * 128 + 2 * lane) = make_float2(o0, o1);
    } else {
        short h0, l0, h1, l1;
        splitf(o0, h0, l0); splitf(o1, h1, l1);
        OUTH[(size_t)node * 64 + lane] = packsplit_hi(h0, h1);
        OUTL[(size_t)node * 64 + lane] = packsplit_hi(l0, l1);
        if (lane == 0) NRM[node] = make_float2(tq, fminf(nq, ATMAX));
    }
}

extern "C" void kernel_launch(void* const* d_in, const int* in_sizes, int n_in,
                              void* d_out, int out_size, void* d_ws, size_t ws_size,
                              hipStream_t stream) {
    const float* x  = (const float*)d_in[0];
    const float* W1 = (const float*)d_in[1];
    const float* b1 = (const float*)d_in[2];
    const float* W2 = (const float*)d_in[3];
    const float* b2 = (const float*)d_in[4];
    const float* ew = (const float*)d_in[5];
    const int* src  = (const int*)d_in[6];
    const int* dst  = (const int*)d_in[7];
    const int N = in_sizes[0] / 128;
    const int E = in_sizes[5];
    float* out = (float*)d_out;

    const int NBUCK = (N + BNODES - 1) >> NBH;
    const int EB = (E + PBE - 1) / PBE;

    char* w = (char*)d_ws;
    unsigned* xt  = (unsigned*)w; w += (size_t)N * 64 * 4;   // bf16 tangent (linear->agg)
    unsigned* xh  = (unsigned*)w; w += (size_t)N * 64 * 4;   // hi (aggact L1 -> linear L2)
    unsigned* xl  = (unsigned*)w; w += (size_t)N * 64 * 4;   // lo
    int2*   csr   = (int2*)w;   w += (size_t)NBUCK * BWIN * 8;
    float2* nrm   = (float2*)w; w += (size_t)N * 8;
    int2*   rp2   = (int2*)w;   w += (size_t)N * 8;
    int2*   staging = (int2*)w; w += (size_t)NBUCK * BCAP * 8;
    unsigned* wh1 = (unsigned*)w; w += 8192 * 4;
    unsigned* wl1 = (unsigned*)w; w += 8192 * 4;
    unsigned* wh2 = (unsigned*)w; w += 8192 * 4;
    unsigned* wl2 = (unsigned*)w; w += 8192 * 4;
    float2* hbuf  = (float2*)w; w += 2 * 65 * 8;
    int*    gcur  = (int*)w;    w += (size_t)NBUCK * 4 + 256;

    hipMemsetAsync(gcur, 0, (size_t)NBUCK * 4, stream);
    k_bucket<<<EB, 256, 0, stream>>>(src, dst, ew, gcur, staging, E, NBUCK);
    k_cbuild<<<NBUCK, 256, 0, stream>>>(gcur, staging, csr, rp2, N);
    k_wprep<<<64, 256, 0, stream>>>(W1, W2, wh1, wl1, wh2, wl2);
    k_bias<<<2, 64, 0, stream>>>(b1, b2, hbuf);

    const int rowblocks = (N + 3) / 4;
    const int ntiles = (N + 15) / 16;
    const int nlb = (ntiles + 3) / 4;

    // layer 1 (encode fused: reads f32 x directly)
    k_linear<1><<<nlb, 256, 0, stream>>>(x, nullptr, nullptr, wh1, wl1, hbuf, nullptr, xt, N);
    k_aggact<<<rowblocks, 256, 0, stream>>>(xt, rp2, csr, nullptr, xh, xl, nrm, N, 0);
    // layer 2 (pre-split inputs from aggact; norms in nrm)
    k_linear<0><<<nlb, 256, 0, stream>>>(nullptr, xh, xl, wh2, wl2, hbuf + 65, nrm, xt, N);
    k_aggact<<<rowblocks, 256, 0, stream>>>(xt, rp2, csr, out, nullptr, nullptr, nullptr, N, 1);
}

// Round 13
// 286.446 us; speedup vs baseline: 1.2522x; 1.0506x over previous
//
#include <hip/hip_runtime.h>
#include <hip/hip_bf16.h>

#define MINN 1e-15f
#define MAXN (1.0f - 4e-3f)
#define ATMAX 3.1063031f   // atanhf(1 - 4e-3)

#define NBH 9              // log2(nodes per bucket)
#define BNODES 512
#define BCAP 10240         // staging capacity per bucket
#define BWIN (BCAP + 4 * BNODES)
#define PBE 8192           // edges per pass-B block

typedef short short8 __attribute__((ext_vector_type(8)));
typedef float f32x4 __attribute__((ext_vector_type(4)));

__device__ __forceinline__ float wsum(float v) {
    v += __shfl_xor(v, 32, 64);
    v += __shfl_xor(v, 16, 64);
    v += __shfl_xor(v, 8, 64);
    v += __shfl_xor(v, 4, 64);
    v += __shfl_xor(v, 2, 64);
    v += __shfl_xor(v, 1, 64);
    return v;
}

// truncation split: f ~= bf16(hi) + bf16(lo), combined rel err ~2^-18
__device__ __forceinline__ void splitf(float f, short& hi, short& lo) {
    unsigned u = __float_as_uint(f);
    hi = (short)(u >> 16);
    float r = f - __uint_as_float(u & 0xffff0000u);
    lo = (short)(__float_as_uint(r) >> 16);
}

__device__ __forceinline__ unsigned packsplit_hi(short ha, short hb) {
    return (unsigned)(unsigned short)ha | ((unsigned)(unsigned short)hb << 16);
}

// RNE bf16 pack of two floats
__device__ __forceinline__ unsigned pack_bf16(float a, float b) {
    unsigned ua = __float_as_uint(a);
    unsigned ub = __float_as_uint(b);
    ua = (ua + 0x7fffu + ((ua >> 16) & 1u)) >> 16;
    ub = (ub + 0x7fffu + ((ub >> 16) & 1u)) & 0xffff0000u;
    return ua | ub;
}

// fast transcendentals (args >= 0 in all uses; err ~2e-7)
__device__ __forceinline__ float tanh_fast(float x) {
    float e = __expf(2.f * x);
    return (e - 1.f) * __builtin_amdgcn_rcpf(e + 1.f);
}
__device__ __forceinline__ float atanh_fast(float x) {
    return 0.5f * __logf((1.f + x) * __builtin_amdgcn_rcpf(1.f - x));
}

// fragment index for A-side buffers: element (row, uint-col c) ->
// tile T=row>>4, kt=c>>4, lg=(c>>2)&3, j=c&3, lr=row&15
__device__ __forceinline__ size_t fragidx(int row, int c) {
    return ((size_t)((row >> 4) * 4 + (c >> 4)) << 8) + ((((c >> 2) & 3) * 16 + (row & 15)) << 2) + (c & 3);
}

// ---------------- pass B: bin edges into 512-node buckets ----------------
__global__ __launch_bounds__(256) void k_bucket(const int* __restrict__ src, const int* __restrict__ dst,
                                                const float* __restrict__ ew, int* __restrict__ gcur,
                                                int2* __restrict__ staging, int E, int NBUCK) {
    __shared__ int hist[512];
    const int tid = threadIdx.x;
    const int e0 = blockIdx.x * PBE;
    for (int i = tid; i < 512; i += 256) hist[i] = 0;
    __syncthreads();
    #pragma unroll 4
    for (int j = 0; j < PBE / 256; j++) {
        int e = e0 + j * 256 + tid;
        if (e < E) atomicAdd(&hist[dst[e] >> NBH], 1);
    }
    __syncthreads();
    for (int b = tid; b < NBUCK; b += 256) {
        int c = hist[b];
        hist[b] = c ? atomicAdd(&gcur[b], c) : 0;
    }
    __syncthreads();
    #pragma unroll 4
    for (int j = 0; j < PBE / 256; j++) {
        int e = e0 + j * 256 + tid;
        if (e < E) {
            int d = dst[e];
            int bkt = d >> NBH;
            int pos = atomicAdd(&hist[bkt], 1);
            if (pos < BCAP)
                staging[(size_t)bkt * BCAP + pos] =
                    make_int2((src[e] & 0x1FFFF) | ((d & (BNODES - 1)) << 17), __float_as_int(ew[e]));
        }
    }
}

// ---------------- pass C: per-bucket CSR build ----------------
__global__ __launch_bounds__(256) void k_cbuild(const int* __restrict__ gcur, const int2* __restrict__ staging,
                                                int2* __restrict__ csr, int2* __restrict__ rp2, int N) {
    __shared__ int cnt[BNODES];
    __shared__ int base[BNODES];
    __shared__ int sbuf[256];
    const int tid = threadIdx.x;
    const int b = blockIdx.x;
    const int bcnt = min(gcur[b], BCAP);
    const int wbase = b * BWIN;
    const int2* st = staging + (size_t)b * BCAP;

    for (int i = tid; i < BNODES; i += 256) cnt[i] = 0;
    __syncthreads();
    for (int i = tid; i < bcnt; i += 256) {
        int nl = (st[i].x >> 17) & (BNODES - 1);
        atomicAdd(&cnt[nl], 1);
    }
    __syncthreads();
    int p0 = (cnt[2 * tid] + 3) & ~3;
    int p1 = (cnt[2 * tid + 1] + 3) & ~3;
    int s = p0 + p1;
    sbuf[tid] = s;
    __syncthreads();
    for (int off = 1; off < 256; off <<= 1) {
        int add = (tid >= off) ? sbuf[tid - off] : 0;
        __syncthreads();
        sbuf[tid] += add;
        __syncthreads();
    }
    int excl = sbuf[tid] - s;
    base[2 * tid] = excl;
    base[2 * tid + 1] = excl + p0;
    __syncthreads();
    for (int i = tid; i < BNODES; i += 256) {
        int node = b * BNODES + i;
        int c = cnt[i];
        int pd = (c + 3) & ~3;
        int gb = wbase + base[i];
        if (node < N) rp2[node] = make_int2(gb, pd);
        for (int k = c; k < pd; k++) csr[gb + k] = make_int2(0, 0);
    }
    __syncthreads();
    for (int i = tid; i < BNODES; i += 256) cnt[i] = wbase + base[i];
    __syncthreads();
    for (int i = tid; i < bcnt; i += 256) {
        int2 p = st[i];
        int nl = (p.x >> 17) & (BNODES - 1);
        int pos = atomicAdd(&cnt[nl], 1);
        csr[pos] = make_int2(p.x & 0x1FFFF, p.y);
    }
}

// ---------------- prep: split W into fragment-ordered bf16 hi/lo ----------------
// WHf frag = ((wid*2+ct)*4+kt): element (lane=lg*16+lr, j) = W[wid*32+2*lr+ct][2c],[2c+1],
// c = kt*16+lg*4+j. One wave load per fragment = contiguous 1KB.
__global__ __launch_bounds__(256) void k_wprep(const float* __restrict__ W1, const float* __restrict__ W2,
                                               unsigned* __restrict__ WH1, unsigned* __restrict__ WL1,
                                               unsigned* __restrict__ WH2, unsigned* __restrict__ WL2) {
    int f = (blockIdx.x & 31) * 256 + threadIdx.x;   // [0, 8192)
    const float* W = (blockIdx.x < 32) ? W1 : W2;
    unsigned* WH = (blockIdx.x < 32) ? WH1 : WH2;
    unsigned* WL = (blockIdx.x < 32) ? WL1 : WL2;
    int frag = f >> 8, rem = f & 255;
    int lane = rem >> 2, j = rem & 3;
    int lr = lane & 15, lg = lane >> 4;
    int wid = frag >> 3, ct = (frag >> 2) & 1, kt = frag & 3;
    int n = wid * 32 + 2 * lr + ct;
    int c = kt * 16 + lg * 4 + j;
    float a = W[n * 128 + 2 * c], b = W[n * 128 + 2 * c + 1];
    short ha, la, hb, lb;
    splitf(a, ha, la); splitf(b, hb, lb);
    WH[f] = packsplit_hi(ha, hb);
    WL[f] = packsplit_hi(la, lb);
}

// ---------------- prep: hyperbolic bias vectors ----------------
__global__ __launch_bounds__(64) void k_bias(const float* __restrict__ B1, const float* __restrict__ B2,
                                             float2* __restrict__ HB) {
    const int lane = threadIdx.x;
    const float* B = (blockIdx.x == 0) ? B1 : B2;
    float2 bb = *(const float2*)(B + 2 * lane);
    float nb2 = wsum(bb.x * bb.x + bb.y * bb.y);
    float nb = fmaxf(sqrtf(nb2), MINN);
    float tbc = fminf(tanh_fast(nb), MAXN);
    float fb = tbc / nb;
    HB[blockIdx.x * 65 + lane] = make_float2(fb * bb.x, fb * bb.y);
    if (lane == 0) HB[blockIdx.x * 65 + 64] = make_float2(tbc * tbc, 0.f);
}

// ---------------- prep: split x into fragment-ordered bf16 hi/lo + norms ----------------
__global__ __launch_bounds__(256) void k_encode(const float* __restrict__ X,
                                                unsigned* __restrict__ XH, unsigned* __restrict__ XL,
                                                float2* __restrict__ NRM, int N) {
    const int lane = threadIdx.x & 63;
    const int wid = threadIdx.x >> 6;
    int row = blockIdx.x * 4 + wid;
    if (row >= N) return;
    float2 u = *(const float2*)(X + (size_t)row * 128 + 2 * lane);
    float n2 = wsum(u.x * u.x + u.y * u.y);
    short h0, l0, h1, l1;
    splitf(u.x, h0, l0); splitf(u.y, h1, l1);
    size_t idx = fragidx(row, lane);
    XH[idx] = packsplit_hi(h0, h1);
    XL[idx] = packsplit_hi(l0, l1);
    if (lane == 0) {
        float n0 = fmaxf(sqrtf(n2), MINN);
        NRM[row] = make_float2(n0, fminf(n0, ATMAX));
    }
}

// ---------------- fused HypLinear: fragment loads + direct-store epilogue ----------------
// Wave owns cols [wid*32, wid*32+32); tile ct covers interleaved cols wid*32+2*lr+ct,
// so a lane's (acc0[r], acc1[r]) is the adjacent pair (2c, 2c+1) -> direct bf16 pack+store.
__global__ __launch_bounds__(256) void k_linear(
    const unsigned* __restrict__ XHf, const unsigned* __restrict__ XLf,
    const unsigned* __restrict__ WHf, const unsigned* __restrict__ WLf,
    const float2* __restrict__ HB, const float2* __restrict__ NRM,
    unsigned* __restrict__ OUT, int N)
{
    __shared__ float pmn[4][16][4];
    __shared__ float pdm[4][16][4];

    const int lane = threadIdx.x & 63;
    const int wid = threadIdx.x >> 6;
    const int lr = lane & 15;
    const int lg = lane >> 4;
    const int tbase = blockIdx.x * 4;

    // B fragments: contiguous 1KB loads
    short8 Bh[2][4], Bl[2][4];
    #pragma unroll
    for (int ct = 0; ct < 2; ct++) {
        #pragma unroll
        for (int kt = 0; kt < 4; kt++) {
            const int fb = ((wid * 2 + ct) * 4 + kt) << 8;
            Bh[ct][kt] = *(const short8*)(WHf + fb + lane * 4);
            Bl[ct][kt] = *(const short8*)(WLf + fb + lane * 4);
        }
    }
    const float2 hbc = HB[wid * 16 + lr];   // hb elems (2c, 2c+1) for c = wid*16+lr
    const float y2 = HB[64].x;

    f32x4 acc[4][2];

    #pragma unroll
    for (int t = 0; t < 4; t++) {
        const int row0 = (tbase + t) << 4;
        if (row0 >= N) break;

        short8 Ah[4], Al[4];
        #pragma unroll
        for (int kt = 0; kt < 4; kt++) {
            const int fa = ((tbase + t) * 4 + kt) << 8;
            Ah[kt] = *(const short8*)(XHf + fa + lane * 4);
            Al[kt] = *(const short8*)(XLf + fa + lane * 4);
        }

        f32x4 a0 = {0.f, 0.f, 0.f, 0.f}, a1 = {0.f, 0.f, 0.f, 0.f};
        #pragma unroll
        for (int kt = 0; kt < 4; kt++) {
            a0 = __builtin_amdgcn_mfma_f32_16x16x32_bf16(Ah[kt], Bh[0][kt], a0, 0, 0, 0);
            a1 = __builtin_amdgcn_mfma_f32_16x16x32_bf16(Ah[kt], Bh[1][kt], a1, 0, 0, 0);
            a0 = __builtin_amdgcn_mfma_f32_16x16x32_bf16(Al[kt], Bh[0][kt], a0, 0, 0, 0);
            a1 = __builtin_amdgcn_mfma_f32_16x16x32_bf16(Al[kt], Bh[1][kt], a1, 0, 0, 0);
            a0 = __builtin_amdgcn_mfma_f32_16x16x32_bf16(Ah[kt], Bl[0][kt], a0, 0, 0, 0);
            a1 = __builtin_amdgcn_mfma_f32_16x16x32_bf16(Ah[kt], Bl[1][kt], a1, 0, 0, 0);
        }
        acc[t][0] = a0; acc[t][1] = a1;

        // per-row partials over this wave's 32 cols; C row = lg*4 + r
        float pm[4], pd[4];
        #pragma unroll
        for (int r = 0; r < 4; r++) {
            pm[r] = a0[r] * a0[r] + a1[r] * a1[r];
            pd[r] = a0[r] * hbc.x + a1[r] * hbc.y;
        }
        #pragma unroll
        for (int s = 1; s <= 8; s <<= 1) {
            #pragma unroll
            for (int r = 0; r < 4; r++) {
                pm[r] += __shfl_xor(pm[r], s, 64);
                pd[r] += __shfl_xor(pd[r], s, 64);
            }
        }
        if (lr == 0) {
            #pragma unroll
            for (int r = 0; r < 4; r++) {
                pmn[t][lg * 4 + r][wid] = pm[r];
                pdm[t][lg * 4 + r][wid] = pd[r];
            }
        }
    }
    __syncthreads();

    #pragma unroll
    for (int t = 0; t < 4; t++) {
        const int row0 = (tbase + t) << 4;
        if (row0 >= N) break;

        // chain for row row0+lr (computed redundantly by the 4 lg groups)
        float4 qm = *(const float4*)pmn[t][lr];
        float4 qd = *(const float4*)pdm[t][lr];
        float mn2 = (qm.x + qm.y) + (qm.z + qm.w);
        float dmb = (qd.x + qd.y) + (qd.z + qd.w);
        const int crow = row0 + lr;
        float caf1 = 0.f, cbs = 0.f;
        if (crow < N) {
            float2 nr = NRM[crow];
            float xn = fmaxf(nr.x, MINN);
            float axn = nr.y;
            float mxn = fmaxf(sqrtf(mn2), MINN);
            float arg = (mxn / xn) * axn;
            float thc = fminf(tanh_fast(arg), MAXN);
            float f1 = thc / mxn;
            float x2 = thc * thc;
            float xy = f1 * dmb;
            float ca = 1.f + 2.f * xy + y2;
            float cb = 1.f - x2;
            float inv = 1.f / fmaxf(1.f + 2.f * xy + x2 * y2, MINN);
            float ng2 = inv * inv * (ca * ca * x2 + 2.f * ca * cb * xy + cb * cb * y2);
            float ng = fmaxf(sqrtf(ng2), MINN);
            float lf = atanh_fast(fminf(ng, MAXN)) / ng;
            float sle = lf * inv;
            caf1 = sle * ca * f1;
            cbs = sle * cb;
        }
        #pragma unroll
        for (int r = 0; r < 4; r++) {
            const int q = lg * 4 + r;
            float c1 = __shfl(caf1, q, 16);
            float c2 = __shfl(cbs, q, 16);
            const int row = row0 + q;
            if (row < N) {
                float o0 = c1 * acc[t][0][r] + c2 * hbc.x;
                float o1 = c1 * acc[t][1][r] + c2 * hbc.y;
                OUT[(size_t)row * 64 + wid * 16 + lr] = pack_bf16(o0, o1);
            }
        }
    }
}

// ---------------- fused aggregation + HypAct ----------------
// last=0: write fragment-ordered hi/lo + NRM; last=1: write f32 to OUTF.
__global__ __launch_bounds__(256) void k_aggact(const unsigned* __restrict__ XT, const int2* __restrict__ rp2,
                                                const int2* __restrict__ csr,
                                                float* __restrict__ OUTF,
                                                unsigned* __restrict__ OUTH, unsigned* __restrict__ OUTL,
                                                float2* __restrict__ NRM, int N, int last) {
    const int lane = threadIdx.x & 63;
    const int wid = threadIdx.x >> 6;
    int node = blockIdx.x * 4 + wid;
    if (node >= N) return;
    int2 rr = rp2[node];
    int b = __builtin_amdgcn_readfirstlane(rr.x);
    int cnt = __builtin_amdgcn_readfirstlane(rr.y);
    int e8 = b + (cnt & ~7);

    float ax[8], ay[8];
    #pragma unroll
    for (int j = 0; j < 8; j++) { ax[j] = 0.f; ay[j] = 0.f; }

    for (int i = b; i < e8; i += 8) {
        int2 c[8];
        #pragma unroll
        for (int j = 0; j < 8; j++) c[j] = csr[i + j];
        unsigned v[8];
        #pragma unroll
        for (int j = 0; j < 8; j++) v[j] = XT[(size_t)c[j].x * 64 + lane];
        #pragma unroll
        for (int j = 0; j < 8; j++) {
            float w = __int_as_float(c[j].y);
            ax[j] = fmaf(w, __uint_as_float(v[j] << 16), ax[j]);
            ay[j] = fmaf(w, __uint_as_float(v[j] & 0xffff0000u), ay[j]);
        }
    }
    if (cnt & 4) {
        int i = e8;
        int2 c[4];
        #pragma unroll
        for (int j = 0; j < 4; j++) c[j] = csr[i + j];
        unsigned v[4];
        #pragma unroll
        for (int j = 0; j < 4; j++) v[j] = XT[(size_t)c[j].x * 64 + lane];
        #pragma unroll
        for (int j = 0; j < 4; j++) {
            float w = __int_as_float(c[j].y);
            ax[j] = fmaf(w, __uint_as_float(v[j] << 16), ax[j]);
            ay[j] = fmaf(w, __uint_as_float(v[j] & 0xffff0000u), ay[j]);
        }
    }
    float a0 = ((ax[0] + ax[1]) + (ax[2] + ax[3])) + ((ax[4] + ax[5]) + (ax[6] + ax[7]));
    float a1 = ((ay[0] + ay[1]) + (ay[2] + ay[3])) + ((ay[4] + ay[5]) + (ay[6] + ay[7]));

    // act: logmap0(proj(expmap0(agg))) = agg * min(n,ATMAX)/n
    float r0 = fmaxf(a0, 0.f), r1 = fmaxf(a1, 0.f);
    float n2 = a0 * a0 + a1 * a1;
    float q2 = r0 * r0 + r1 * r1;
    #pragma unroll
    for (int s = 32; s; s >>= 1) {
        n2 += __shfl_xor(n2, s, 64);
        q2 += __shfl_xor(q2, s, 64);
    }
    float n = fmaxf(sqrtf(n2), MINN);
    float cp = fminf(n, ATMAX) / n;
    float nq = fmaxf(cp * sqrtf(q2), MINN);
    float tq = fminf(tanh_fast(nq), MAXN);
    float f2 = tq / nq;
    float sc = f2 * cp;
    float o0 = sc * r0, o1 = sc * r1;
    if (last) {
        *(float2*)(OUTF + (size_t)node * 128 + 2 * lane) = make_float2(o0, o1);
    } else {
        short h0, l0, h1, l1;
        splitf(o0, h0, l0); splitf(o1, h1, l1);
        size_t idx = fragidx(node, lane);
        OUTH[idx] = packsplit_hi(h0, h1);
        OUTL[idx] = packsplit_hi(l0, l1);
        if (lane == 0) NRM[node] = make_float2(tq, fminf(nq, ATMAX));
    }
}

extern "C" void kernel_launch(void* const* d_in, const int* in_sizes, int n_in,
                              void* d_out, int out_size, void* d_ws, size_t ws_size,
                              hipStream_t stream) {
    const float* x  = (const float*)d_in[0];
    const float* W1 = (const float*)d_in[1];
    const float* b1 = (const float*)d_in[2];
    const float* W2 = (const float*)d_in[3];
    const float* b2 = (const float*)d_in[4];
    const float* ew = (const float*)d_in[5];
    const int* src  = (const int*)d_in[6];
    const int* dst  = (const int*)d_in[7];
    const int N = in_sizes[0] / 128;
    const int E = in_sizes[5];
    float* out = (float*)d_out;

    const int NBUCK = (N + BNODES - 1) >> NBH;
    const int EB = (E + PBE - 1) / PBE;
    const int ntiles = (N + 15) / 16;

    char* w = (char*)d_ws;
    unsigned* xt  = (unsigned*)w; w += (size_t)N * 64 * 4;          // bf16 tangent (linear->agg), row-major
    unsigned* xhf = (unsigned*)w; w += (size_t)ntiles * 1024 * 4;   // fragment-ordered hi
    unsigned* xlf = (unsigned*)w; w += (size_t)ntiles * 1024 * 4;   // fragment-ordered lo
    int2*   csr   = (int2*)w;   w += (size_t)NBUCK * BWIN * 8;
    float2* nrm   = (float2*)w; w += (size_t)N * 8;
    int2*   rp2   = (int2*)w;   w += (size_t)N * 8;
    int2*   staging = (int2*)w; w += (size_t)NBUCK * BCAP * 8;
    unsigned* wh1 = (unsigned*)w; w += 8192 * 4;
    unsigned* wl1 = (unsigned*)w; w += 8192 * 4;
    unsigned* wh2 = (unsigned*)w; w += 8192 * 4;
    unsigned* wl2 = (unsigned*)w; w += 8192 * 4;
    float2* hbuf  = (float2*)w; w += 2 * 65 * 8;
    int*    gcur  = (int*)w;    w += (size_t)NBUCK * 4 + 256;

    hipMemsetAsync(gcur, 0, (size_t)NBUCK * 4, stream);
    k_bucket<<<EB, 256, 0, stream>>>(src, dst, ew, gcur, staging, E, NBUCK);
    k_cbuild<<<NBUCK, 256, 0, stream>>>(gcur, staging, csr, rp2, N);
    k_wprep<<<64, 256, 0, stream>>>(W1, W2, wh1, wl1, wh2, wl2);
    k_bias<<<2, 64, 0, stream>>>(b1, b2, hbuf);

    const int rowblocks = (N + 3) / 4;
    const int nlb = (ntiles + 3) / 4;

    // encode: f32 x -> fragment-ordered hi/lo + norms
    k_encode<<<rowblocks, 256, 0, stream>>>(x, xhf, xlf, nrm, N);
    // layer 1
    k_linear<<<nlb, 256, 0, stream>>>(xhf, xlf, wh1, wl1, hbuf, nrm, xt, N);
    k_aggact<<<rowblocks, 256, 0, stream>>>(xt, rp2, csr, nullptr, xhf, xlf, nrm, N, 0);
    // layer 2 (fragment inputs + norms from aggact)
    k_linear<<<nlb, 256, 0, stream>>>(xhf, xlf, wh2, wl2, hbuf + 65, nrm, xt, N);
    k_aggact<<<rowblocks, 256, 0, stream>>>(xt, rp2, csr, out, nullptr, nullptr, nullptr, N, 1);
}